// Round 10
// baseline (416.985 us; speedup 1.0000x reference)
//
#include <hip/hip_runtime.h>
#include <hip/hip_bf16.h>
#include <cmath>

// Block_15006615734251: fused transformer block, mixed sigmoid/softmax attention.
// B=2, N=4096, C=384, H=6, HD=64. Outputs: x_out [2,4096,384] f32, attn_obj [2,3,4096,4096] f32.
//
// R10 (from R9 post-mortem: pose is compute-bound and pays 2:1 CU imbalance;
// its K/V are L2-resident so LDS staging + barriers are pure overhead):
//  - attn_obj: unchanged from R9 (full sweep, staged, direct ctx1T; BW-bound)
//  - attn_pose: column-split x4 (1536 blocks, uniform), NO LDS K/V staging,
//    NO main-loop barriers: K/V b-frags are contiguous 16B/lane global loads
//    (L2-resident). f32 partials + reduce_pose restored (~50 MB RT, 8 us).

typedef __hip_bfloat16 bf16;
typedef __attribute__((ext_vector_type(8))) short short8;
typedef __attribute__((ext_vector_type(4))) short s16x4;
typedef __attribute__((ext_vector_type(4))) float f32x4;

#define MFMA16(a, b, c) __builtin_amdgcn_mfma_f32_16x16x32_bf16((a), (b), (c), 0, 0, 0)

__device__ __forceinline__ void async16(const void* g, void* l) {
  __builtin_amdgcn_global_load_lds(
      (const __attribute__((address_space(1))) void*)g,
      (__attribute__((address_space(3))) void*)l, 16, 0, 0);
}

__device__ __forceinline__ short f2bs(float v) {
  union { bf16 b; short s; } u;
  u.b = __float2bfloat16(v);
  return u.s;
}

// ---------------- LayerNorm (+ fused weight cvt when FIRST) ----------------
template <bool FIRST>
__global__ __launch_bounds__(256) void ln_fwd(const float* __restrict__ x,
                                              const float* __restrict__ gamma,
                                              const float* __restrict__ beta,
                                              bf16* __restrict__ out,
                                              const float* __restrict__ w0,
                                              const float* __restrict__ w1,
                                              const float* __restrict__ w2,
                                              const float* __restrict__ w3,
                                              bf16* __restrict__ o0, bf16* __restrict__ o1,
                                              bf16* __restrict__ o2, bf16* __restrict__ o3) {
  const int bx = blockIdx.x;
  if (FIRST) {
    if (bx >= 2048) {
      int i = (bx - 2048) * 256 + threadIdx.x;  // f32x4 index
      const int n0 = 442368 / 4, n1 = 73728 / 4, n2 = 589824 / 4, n3 = 589824 / 4;
      const float* src;
      bf16* dst;
      if (i < n0) { src = w0; dst = o0; }
      else if ((i -= n0) < n1) { src = w1; dst = o1; }
      else if ((i -= n1) < n2) { src = w2; dst = o2; }
      else { i -= n2; src = w3; dst = o3; }
      f32x4 v = *(const f32x4*)(src + (size_t)i * 4);
      s16x4 o;
#pragma unroll
      for (int e = 0; e < 4; ++e) o[e] = f2bs(v[e]);
      *(s16x4*)(dst + (size_t)i * 4) = o;
      return;
    }
  }
  const int row = bx * 4 + (threadIdx.x >> 6);
  const int l = threadIdx.x & 63;
  const float* xr = x + (size_t)row * 384;
  float v[6];
  float s = 0.f, q = 0.f;
#pragma unroll
  for (int i = 0; i < 6; ++i) {
    v[i] = xr[l + i * 64];
    s += v[i];
    q += v[i] * v[i];
  }
#pragma unroll
  for (int m = 1; m < 64; m <<= 1) {
    s += __shfl_xor(s, m);
    q += __shfl_xor(q, m);
  }
  float mean = s * (1.0f / 384.0f);
  float var = q * (1.0f / 384.0f) - mean * mean;
  float rstd = rsqrtf(var + 1e-5f);
  bf16* orow = out + (size_t)row * 384;
#pragma unroll
  for (int i = 0; i < 6; ++i)
    orow[l + i * 64] = __float2bfloat16((v[i] - mean) * rstd * gamma[l + i * 64] + beta[l + i * 64]);
}

// ---------------- GEMM NT 128x128 (m97 structure) ----------------
template <int EPI>
__global__ __launch_bounds__(256) void gemm128(const bf16* __restrict__ A,
                                               const bf16* __restrict__ Bm, int M, int N, int K,
                                               const float* __restrict__ bias,
                                               bf16* __restrict__ outb) {
  __shared__ __attribute__((aligned(16))) short As[128][64];
  __shared__ __attribute__((aligned(16))) short Bs[128][64];
  const int t = threadIdx.x;
  const int l = t & 63;
  const int w = t >> 6;
  const int wm = w >> 1, wn = w & 1;
  const int bm = blockIdx.y * 128, bn = blockIdx.x * 128;

  f32x4 acc[4][4] = {};
  const int r8 = t >> 3;
  const int c8 = (t & 7) * 8;
  const bf16* Ab = A + (size_t)(bm + r8) * K + c8;
  const bf16* Bb = Bm + (size_t)(bn + r8) * K + c8;

  for (int kt = 0; kt < K; kt += 64) {
    __syncthreads();
#pragma unroll
    for (int i = 0; i < 4; ++i)
      async16(Ab + (size_t)(i * 32) * K + kt, &As[i * 32 + r8][c8]);
#pragma unroll
    for (int i = 0; i < 4; ++i)
      async16(Bb + (size_t)(i * 32) * K + kt, &Bs[i * 32 + r8][c8]);
    __syncthreads();
#pragma unroll
    for (int ks = 0; ks < 2; ++ks) {
      short8 a[4], b[4];
#pragma unroll
      for (int i = 0; i < 4; ++i)
        a[i] = *(const short8*)&As[wm * 64 + i * 16 + (l & 15)][ks * 32 + (l >> 4) * 8];
#pragma unroll
      for (int i = 0; i < 4; ++i)
        b[i] = *(const short8*)&Bs[wn * 64 + i * 16 + (l & 15)][ks * 32 + (l >> 4) * 8];
#pragma unroll
      for (int i = 0; i < 4; ++i)
#pragma unroll
        for (int j = 0; j < 4; ++j) acc[i][j] = MFMA16(a[i], b[j], acc[i][j]);
    }
  }

#pragma unroll
  for (int i = 0; i < 4; ++i) {
#pragma unroll
    for (int j = 0; j < 4; ++j) {
#pragma unroll
      for (int r = 0; r < 4; ++r) {
        int row = bm + wm * 64 + i * 16 + (l >> 4) * 4 + r;
        int col = bn + wn * 64 + j * 16 + (l & 15);
        float v = acc[i][j][r];
        if (EPI == 0) {
          int three = col / 384;
          int rem = col - three * 384;
          int head = rem >> 6;
          int hd = rem & 63;
          int bb = row >> 12;
          int n = row & 4095;
          const size_t QSZ = (size_t)2 * 6 * 4096 * 64;
          if (three < 2) {
            size_t di = ((((size_t)three * 2 + bb) * 6 + head) * 4096 + n) * 64 + hd;
            outb[di] = __float2bfloat16(v);
          } else {
            size_t di = 2 * QSZ + (((size_t)bb * 6 + head) * 64 + hd) * 4096 + n;
            outb[di] = __float2bfloat16(v);
          }
        } else {
          float u = v + bias[col];
          float z = 0.7978845608f * (u + 0.044715f * u * u * u);
          float e = __builtin_amdgcn_exp2f(z * 2.885390082f);
          float th = 1.0f - 2.0f * __builtin_amdgcn_rcpf(e + 1.0f);
          outb[(size_t)row * N + col] = __float2bfloat16(0.5f * u * (1.0f + th));
        }
      }
    }
  }
}

// ---------------- GEMM NT 64x64 dbuf: C = A*B^T + bias + resid (f32) ----------------
__global__ __launch_bounds__(256) void gemm64sq(const bf16* __restrict__ A,
                                                const bf16* __restrict__ Bm, int M, int N, int K,
                                                const float* __restrict__ bias,
                                                const float* __restrict__ resid,
                                                float* __restrict__ outf) {
  __shared__ __attribute__((aligned(16))) short As[2][64][64];
  __shared__ __attribute__((aligned(16))) short Bs[2][64][64];
  const int t = threadIdx.x;
  const int l = t & 63;
  const int w = t >> 6;
  const int wm = w >> 1, wn = w & 1;
  const int bm = blockIdx.y * 64, bn = blockIdx.x * 64;
  const int r8 = t >> 3, c8 = (t & 7) * 8;

  const bf16* Ab = A + (size_t)(bm + r8) * K + c8;
  const bf16* Bb = Bm + (size_t)(bn + r8) * K + c8;

  f32x4 acc[2][2] = {};

  auto stage = [&](int kt, int bf) {
    async16(Ab + kt, &As[bf][r8][c8]);
    async16(Ab + (size_t)32 * K + kt, &As[bf][32 + r8][c8]);
    async16(Bb + kt, &Bs[bf][r8][c8]);
    async16(Bb + (size_t)32 * K + kt, &Bs[bf][32 + r8][c8]);
  };

  stage(0, 0);
  int bf = 0;
  for (int kt = 0; kt < K; kt += 64) {
    __syncthreads();
    if (kt + 64 < K) stage(kt + 64, bf ^ 1);
#pragma unroll
    for (int ks = 0; ks < 2; ++ks) {
      short8 a[2], b[2];
#pragma unroll
      for (int i = 0; i < 2; ++i)
        a[i] = *(const short8*)&As[bf][wm * 32 + i * 16 + (l & 15)][ks * 32 + (l >> 4) * 8];
#pragma unroll
      for (int j = 0; j < 2; ++j)
        b[j] = *(const short8*)&Bs[bf][wn * 32 + j * 16 + (l & 15)][ks * 32 + (l >> 4) * 8];
#pragma unroll
      for (int i = 0; i < 2; ++i)
#pragma unroll
        for (int j = 0; j < 2; ++j) acc[i][j] = MFMA16(a[i], b[j], acc[i][j]);
    }
    bf ^= 1;
  }

#pragma unroll
  for (int i = 0; i < 2; ++i) {
#pragma unroll
    for (int j = 0; j < 2; ++j) {
#pragma unroll
      for (int r = 0; r < 4; ++r) {
        int row = bm + wm * 32 + i * 16 + (l >> 4) * 4 + r;
        int col = bn + wn * 32 + j * 16 + (l & 15);
        size_t di = (size_t)row * N + col;
        outf[di] = acc[i][j][r] + bias[col] + resid[di];
      }
    }
  }
}

// ---------------- attn_obj: QBLK=64, full column sweep, staged, direct ctx1T ----------------
__global__ __launch_bounds__(256) void attn_obj(const bf16* __restrict__ qkvb,
                                                float* __restrict__ aout,
                                                bf16* __restrict__ ctx1T) {
  const int bh = blockIdx.y, b = bh / 3, h = bh - b * 3;
  const int row0 = blockIdx.x * 64;
  const int t = threadIdx.x, l = t & 63, w = t >> 6;

  const size_t HSZ = (size_t)4096 * 64;
  const size_t QSZ = (size_t)2 * 6 * 4096 * 64;
  const bf16* qp = qkvb + (size_t)(b * 6 + h) * HSZ;
  const bf16* kp = qkvb + QSZ + (size_t)(b * 6 + h) * HSZ;
  const bf16* vbase = qkvb + 2 * QSZ + (size_t)((b * 6 + h + 3) * 64) * 4096;

  __shared__ __attribute__((aligned(16))) short Ks[2][64][64];
  __shared__ __attribute__((aligned(16))) short Vs[2][64][64];
  __shared__ __attribute__((aligned(16))) float Sf[4][16][68];

  short8 aq[2];
  {
    int qrow = row0 + w * 16 + (l & 15);
    const bf16* qq = qp + (size_t)qrow * 64 + (l >> 4) * 8;
    aq[0] = *(const short8*)(qq);
    aq[1] = *(const short8*)(qq + 32);
  }

  const int r8 = t >> 3, c8 = (t & 7) * 8;
  const int sc = c8 ^ ((r8 & 7) * 8);

  auto stage = [&](int ct, int bf) {
    const bf16* kb = kp + (size_t)(ct * 64) * 64;
    async16(kb + (size_t)r8 * 64 + sc, &Ks[bf][r8][c8]);
    async16(kb + (size_t)(32 + r8) * 64 + sc, &Ks[bf][32 + r8][c8]);
    const bf16* vb = vbase + ct * 64;
    async16(vb + (size_t)r8 * 4096 + sc, &Vs[bf][r8][c8]);
    async16(vb + (size_t)(32 + r8) * 4096 + sc, &Vs[bf][32 + r8][c8]);
  };

  f32x4 cacc[4] = {};
  const float K1 = -0.18033688f;  // -scale*log2(e)

  float* sfw = &Sf[w][0][0];
  stage(0, 0);
  int bf = 0;
  for (int ct = 0; ct < 64; ++ct) {
    __syncthreads();
    if (ct < 63) stage(ct + 1, bf ^ 1);

    f32x4 sacc[4] = {};
#pragma unroll
    for (int ks = 0; ks < 2; ++ks) {
      short8 bk[4];
#pragma unroll
      for (int j = 0; j < 4; ++j) {
        int rr = j * 16 + (l & 15);
        int ec = (ks * 32 + (l >> 4) * 8) ^ ((rr & 7) * 8);
        bk[j] = *(const short8*)&Ks[bf][rr][ec];
      }
      __builtin_amdgcn_s_setprio(1);
#pragma unroll
      for (int j = 0; j < 4; ++j) sacc[j] = MFMA16(aq[ks], bk[j], sacc[j]);
      __builtin_amdgcn_s_setprio(0);
    }

#pragma unroll
    for (int j = 0; j < 4; ++j) {
#pragma unroll
      for (int r = 0; r < 4; ++r) {
        float v = __builtin_amdgcn_rcpf(1.0f + __builtin_amdgcn_exp2f(sacc[j][r] * K1));
        sfw[((l >> 4) * 4 + r) * 68 + j * 16 + (l & 15)] = v;
      }
    }

    short8 pa[2];
#pragma unroll
    for (int ks = 0; ks < 2; ++ks) {
      const float* sp = &sfw[(l & 15) * 68 + ks * 32 + (l >> 4) * 8];
      f32x4 f0 = *(const f32x4*)sp;
      f32x4 f1 = *(const f32x4*)(sp + 4);
      short8 a;
#pragma unroll
      for (int e = 0; e < 4; ++e) a[e] = f2bs(f0[e]);
#pragma unroll
      for (int e = 0; e < 4; ++e) a[4 + e] = f2bs(f1[e]);
      pa[ks] = a;
    }

    {
      float* ab = aout + (size_t)bh * 4096 * 4096 +
                  (size_t)(row0 + w * 16) * 4096 + ct * 64;
#pragma unroll
      for (int i = 0; i < 4; ++i) {
        f32x4 vv = *(const f32x4*)&sfw[(4 * i + (l >> 4)) * 68 + (l & 15) * 4];
        *(f32x4*)(ab + (size_t)(4 * i + (l >> 4)) * 4096 + (l & 15) * 4) = vv;
      }
    }

#pragma unroll
    for (int ks = 0; ks < 2; ++ks) {
      short8 bv[4];
#pragma unroll
      for (int j = 0; j < 4; ++j) {
        int rr = j * 16 + (l & 15);
        int ec = (ks * 32 + (l >> 4) * 8) ^ ((rr & 7) * 8);
        bv[j] = *(const short8*)&Vs[bf][rr][ec];
      }
      __builtin_amdgcn_s_setprio(1);
#pragma unroll
      for (int j = 0; j < 4; ++j) cacc[j] = MFMA16(pa[ks], bv[j], cacc[j]);
      __builtin_amdgcn_s_setprio(0);
    }
    bf ^= 1;
  }

  // transpose ctx [n][hd] -> ctx1T [bh][hd][n] via LDS (reuse Ks)
  __syncthreads();
  short(*S)[66] = (short(*)[66]) & Ks[0][0][0];
#pragma unroll
  for (int j = 0; j < 4; ++j)
#pragma unroll
    for (int r = 0; r < 4; ++r)
      S[w * 16 + (l >> 4) * 4 + r][j * 16 + (l & 15)] = f2bs(cacc[j][r]);
  __syncthreads();
  const int hd = t >> 2, nb = (t & 3) * 16;
  short8 o0, o1;
#pragma unroll
  for (int k = 0; k < 8; ++k) o0[k] = S[nb + k][hd];
#pragma unroll
  for (int k = 0; k < 8; ++k) o1[k] = S[nb + 8 + k][hd];
  short* dst = (short*)(ctx1T + ((size_t)bh * 64 + hd) * 4096 + row0 + nb);
  *(short8*)dst = o0;
  *(short8*)(dst + 8) = o1;
}

// ---------------- attn_pose: split x4, NO staging, NO main-loop barriers ----------------
// P = exp(QK^T/8); K/V b-frags direct from global (L2-resident). Grid (64, 4, 6).
__global__ __launch_bounds__(256) void attn_pose(const bf16* __restrict__ qkvb,
                                                 const bf16* __restrict__ ctx1T,
                                                 float* __restrict__ part,
                                                 float* __restrict__ lpart) {
  const int bh = blockIdx.z, b = bh / 3, h = bh - b * 3;
  const int row0 = blockIdx.x * 64;
  const int cbase = blockIdx.y * 1024;
  const int t = threadIdx.x, l = t & 63, w = t >> 6;

  const size_t HSZ = (size_t)4096 * 64;
  const size_t QSZ = (size_t)2 * 6 * 4096 * 64;
  const bf16* qp = qkvb + (size_t)(b * 6 + h + 3) * HSZ;
  const bf16* kp = qkvb + QSZ + (size_t)(b * 6 + h + 3) * HSZ;
  const bf16* vbase = ctx1T + (size_t)(bh * 64) * 4096;

  __shared__ __attribute__((aligned(16))) float Sf[4][16][68];

  short8 aq[2];
  {
    int qrow = row0 + w * 16 + (l & 15);
    const bf16* qq = qp + (size_t)qrow * 64 + (l >> 4) * 8;
    aq[0] = *(const short8*)(qq);
    aq[1] = *(const short8*)(qq + 32);
  }

  f32x4 cacc[4] = {};
  float lp[4] = {0.f, 0.f, 0.f, 0.f};
  const float K2 = 0.18033688f;  // scale*log2(e)

  // per-lane frag addresses (advance by 64 cols per tile)
  const bf16* kfp = kp + (size_t)(cbase + (l & 15)) * 64 + (l >> 4) * 8;  // + j*16*64 + ks*32
  const bf16* vfp = vbase + (size_t)(l & 15) * 4096 + cbase + (l >> 4) * 8;  // + j*16*4096 + ks*32

  float* sfw = &Sf[w][0][0];
  for (int ct = 0; ct < 16; ++ct) {
    // ---- QK^T: K frags direct from global ----
    f32x4 sacc[4] = {};
    short8 bk[2][4];
#pragma unroll
    for (int ks = 0; ks < 2; ++ks)
#pragma unroll
      for (int j = 0; j < 4; ++j)
        bk[ks][j] = *(const short8*)(kfp + (size_t)(ct * 64 + j * 16) * 64 + ks * 32);
#pragma unroll
    for (int ks = 0; ks < 2; ++ks) {
      __builtin_amdgcn_s_setprio(1);
#pragma unroll
      for (int j = 0; j < 4; ++j) sacc[j] = MFMA16(aq[ks], bk[ks][j], sacc[j]);
      __builtin_amdgcn_s_setprio(0);
    }

    // ---- V frags (issue early, consume after transform) ----
    short8 bv[2][4];
#pragma unroll
    for (int ks = 0; ks < 2; ++ks)
#pragma unroll
      for (int j = 0; j < 4; ++j)
        bv[ks][j] = *(const short8*)(vfp + (size_t)(j * 16) * 4096 + ct * 64 + ks * 32);

    // ---- transform -> Sf (per-wave, no barrier) ----
#pragma unroll
    for (int j = 0; j < 4; ++j) {
#pragma unroll
      for (int r = 0; r < 4; ++r) {
        float v = __builtin_amdgcn_exp2f(sacc[j][r] * K2);
        lp[r] += v;
        sfw[((l >> 4) * 4 + r) * 68 + j * 16 + (l & 15)] = v;
      }
    }

    short8 pa[2];
#pragma unroll
    for (int ks = 0; ks < 2; ++ks) {
      const float* sp = &sfw[(l & 15) * 68 + ks * 32 + (l >> 4) * 8];
      f32x4 f0 = *(const f32x4*)sp;
      f32x4 f1 = *(const f32x4*)(sp + 4);
      short8 a;
#pragma unroll
      for (int e = 0; e < 4; ++e) a[e] = f2bs(f0[e]);
#pragma unroll
      for (int e = 0; e < 4; ++e) a[4 + e] = f2bs(f1[e]);
      pa[ks] = a;
    }

    // ---- PV ----
#pragma unroll
    for (int ks = 0; ks < 2; ++ks) {
      __builtin_amdgcn_s_setprio(1);
#pragma unroll
      for (int j = 0; j < 4; ++j) cacc[j] = MFMA16(pa[ks], bv[ks][j], cacc[j]);
      __builtin_amdgcn_s_setprio(0);
    }
  }

  // ---- partial ctx (f32) + l partials ----
  float* pb = part + ((size_t)(blockIdx.y * 6 + bh) * 4096 + row0 + w * 16) * 64;
#pragma unroll
  for (int j = 0; j < 4; ++j)
#pragma unroll
    for (int r = 0; r < 4; ++r)
      pb[(size_t)((l >> 4) * 4 + r) * 64 + j * 16 + (l & 15)] = cacc[j][r];

#pragma unroll
  for (int r = 0; r < 4; ++r) {
#pragma unroll
    for (int m = 1; m < 16; m <<= 1) lp[r] += __shfl_xor(lp[r], m);
  }
  if ((l & 15) == 0) {
    float* lb = lpart + (size_t)(blockIdx.y * 6 + bh) * 4096 + row0 + w * 16 + (l >> 4) * 4;
#pragma unroll
    for (int r = 0; r < 4; ++r) lb[r] = lp[r];
  }
}

// ---------------- reduce pose partials -> ctxf bf16 [b][n][192] ----------------
__global__ __launch_bounds__(256) void reduce_pose(const float* __restrict__ part,
                                                   const float* __restrict__ lpart,
                                                   bf16* __restrict__ ctxf) {
  const int idx = blockIdx.x * 256 + threadIdx.x;
  const int hd4 = idx & 15;
  const int n = (idx >> 4) & 4095;
  const int bh = idx >> 16;
  const size_t CS = (size_t)6 * 4096 * 64, CL = (size_t)6 * 4096;
  f32x4 s = {};
  float lt = 0.f;
#pragma unroll
  for (int c = 0; c < 4; ++c) {
    s += *(const f32x4*)(part + c * CS + ((size_t)bh * 4096 + n) * 64 + hd4 * 4);
    lt += lpart[c * CL + (size_t)bh * 4096 + n];
  }
  float inv = 1.0f / lt;
  int b = bh / 3, h = bh - b * 3;
  s16x4 o;
#pragma unroll
  for (int e = 0; e < 4; ++e) o[e] = f2bs(s[e] * inv);
  *(s16x4*)(ctxf + ((size_t)b * 4096 + n) * 192 + h * 64 + hd4 * 4) = o;
}

// ---------------- launch ----------------
extern "C" void kernel_launch(void* const* d_in, const int* in_sizes, int n_in,
                              void* d_out, int out_size, void* d_ws, size_t ws_size,
                              hipStream_t stream) {
  const float* x      = (const float*)d_in[0];
  const float* qkv_w  = (const float*)d_in[1];
  const float* proj_w = (const float*)d_in[2];
  const float* proj_b = (const float*)d_in[3];
  const float* gamma1 = (const float*)d_in[4];
  const float* beta1  = (const float*)d_in[5];
  const float* gamma2 = (const float*)d_in[6];
  const float* beta2  = (const float*)d_in[7];
  const float* fc1_w  = (const float*)d_in[8];
  const float* fc1_b  = (const float*)d_in[9];
  const float* fc2_w  = (const float*)d_in[10];
  const float* fc2_b  = (const float*)d_in[11];

  float* out_x = (float*)d_out;
  float* out_attn = out_x + (size_t)2 * 4096 * 384;

  char* ws = (char*)d_ws;
  size_t off = 0;
  auto alloc = [&](size_t bytes) -> void* {
    void* p = ws + off;
    off += (bytes + 255) & ~(size_t)255;
    return p;
  };
  bf16* qkv_w_b  = (bf16*)alloc((size_t)1152 * 384 * 2);
  bf16* proj_w_b = (bf16*)alloc((size_t)384 * 192 * 2);
  bf16* fc1_w_b  = (bf16*)alloc((size_t)1536 * 384 * 2);
  bf16* fc2_w_b  = (bf16*)alloc((size_t)384 * 1536 * 2);
  bf16* h1    = (bf16*)alloc((size_t)8192 * 384 * 2);
  bf16* qkvb  = (bf16*)alloc((size_t)3 * 2 * 6 * 4096 * 64 * 2);
  float* cpp  = (float*)alloc((size_t)4 * 6 * 4096 * 64 * 4);
  float* lpp  = (float*)alloc((size_t)4 * 6 * 4096 * 4);
  bf16* ctx1T = (bf16*)alloc((size_t)6 * 64 * 4096 * 2);
  bf16* ctxf  = (bf16*)alloc((size_t)2 * 4096 * 192 * 2);
  float* x2   = (float*)alloc((size_t)8192 * 384 * 4);
  bf16* h2    = (bf16*)alloc((size_t)8192 * 384 * 2);
  bf16* h3    = (bf16*)alloc((size_t)8192 * 1536 * 2);

  ln_fwd<true><<<3704, 256, 0, stream>>>(x, gamma1, beta1, h1,
                                         qkv_w, proj_w, fc1_w, fc2_w,
                                         qkv_w_b, proj_w_b, fc1_w_b, fc2_w_b);

  gemm128<0><<<dim3(9, 64), 256, 0, stream>>>(h1, qkv_w_b, 8192, 1152, 384,
                                              nullptr, qkvb);

  attn_obj<<<dim3(64, 6), 256, 0, stream>>>(qkvb, out_attn, ctx1T);
  attn_pose<<<dim3(64, 4, 6), 256, 0, stream>>>(qkvb, ctx1T, cpp, lpp);
  reduce_pose<<<1536, 256, 0, stream>>>(cpp, lpp, ctxf);

  gemm64sq<<<dim3(6, 128), 256, 0, stream>>>(ctxf, proj_w_b, 8192, 384, 192,
                                             proj_b, x, x2);
  ln_fwd<false><<<2048, 256, 0, stream>>>(x2, gamma2, beta2, h2,
                                          nullptr, nullptr, nullptr, nullptr,
                                          nullptr, nullptr, nullptr, nullptr);
  gemm128<2><<<dim3(12, 64), 256, 0, stream>>>(h2, fc1_w_b, 8192, 1536, 384,
                                               fc1_b, h3);
  gemm64sq<<<dim3(6, 128), 256, 0, stream>>>(h3, fc2_w_b, 8192, 384, 1536,
                                             fc2_b, x2, out_x);
}

// Round 11
// 294.796 us; speedup vs baseline: 1.4145x; 1.4145x over previous
//
#include <hip/hip_runtime.h>
#include <hip/hip_bf16.h>
#include <cmath>

// Block_15006615734251: fused transformer block, mixed sigmoid/softmax attention.
// B=2, N=4096, C=384, H=6, HD=64. Outputs: x_out [2,4096,384] f32, attn_obj [2,3,4096,4096] f32.
//
// R11 = measured best-of recombination:
//  - attn_obj: R9 variant (QBLK=64 full sweep, LDS-staged, direct ctx1T output;
//    BW-bound -> tolerates 384-block imbalance; kills reduce_obj + 25 MB RT)
//  - attn_pose: R7 variant (QBLK=128, col-split x4, 768 blocks uniform, staged)
//  - R10's direct-global b-frags REVERTED (uncoalesced 64-txn gathers, +108 us)

typedef __hip_bfloat16 bf16;
typedef __attribute__((ext_vector_type(8))) short short8;
typedef __attribute__((ext_vector_type(4))) short s16x4;
typedef __attribute__((ext_vector_type(4))) float f32x4;

#define MFMA16(a, b, c) __builtin_amdgcn_mfma_f32_16x16x32_bf16((a), (b), (c), 0, 0, 0)

__device__ __forceinline__ void async16(const void* g, void* l) {
  __builtin_amdgcn_global_load_lds(
      (const __attribute__((address_space(1))) void*)g,
      (__attribute__((address_space(3))) void*)l, 16, 0, 0);
}

__device__ __forceinline__ short f2bs(float v) {
  union { bf16 b; short s; } u;
  u.b = __float2bfloat16(v);
  return u.s;
}

// ---------------- LayerNorm (+ fused weight cvt when FIRST) ----------------
template <bool FIRST>
__global__ __launch_bounds__(256) void ln_fwd(const float* __restrict__ x,
                                              const float* __restrict__ gamma,
                                              const float* __restrict__ beta,
                                              bf16* __restrict__ out,
                                              const float* __restrict__ w0,
                                              const float* __restrict__ w1,
                                              const float* __restrict__ w2,
                                              const float* __restrict__ w3,
                                              bf16* __restrict__ o0, bf16* __restrict__ o1,
                                              bf16* __restrict__ o2, bf16* __restrict__ o3) {
  const int bx = blockIdx.x;
  if (FIRST) {
    if (bx >= 2048) {
      int i = (bx - 2048) * 256 + threadIdx.x;  // f32x4 index
      const int n0 = 442368 / 4, n1 = 73728 / 4, n2 = 589824 / 4, n3 = 589824 / 4;
      const float* src;
      bf16* dst;
      if (i < n0) { src = w0; dst = o0; }
      else if ((i -= n0) < n1) { src = w1; dst = o1; }
      else if ((i -= n1) < n2) { src = w2; dst = o2; }
      else { i -= n2; src = w3; dst = o3; }
      f32x4 v = *(const f32x4*)(src + (size_t)i * 4);
      s16x4 o;
#pragma unroll
      for (int e = 0; e < 4; ++e) o[e] = f2bs(v[e]);
      *(s16x4*)(dst + (size_t)i * 4) = o;
      return;
    }
  }
  const int row = bx * 4 + (threadIdx.x >> 6);
  const int l = threadIdx.x & 63;
  const float* xr = x + (size_t)row * 384;
  float v[6];
  float s = 0.f, q = 0.f;
#pragma unroll
  for (int i = 0; i < 6; ++i) {
    v[i] = xr[l + i * 64];
    s += v[i];
    q += v[i] * v[i];
  }
#pragma unroll
  for (int m = 1; m < 64; m <<= 1) {
    s += __shfl_xor(s, m);
    q += __shfl_xor(q, m);
  }
  float mean = s * (1.0f / 384.0f);
  float var = q * (1.0f / 384.0f) - mean * mean;
  float rstd = rsqrtf(var + 1e-5f);
  bf16* orow = out + (size_t)row * 384;
#pragma unroll
  for (int i = 0; i < 6; ++i)
    orow[l + i * 64] = __float2bfloat16((v[i] - mean) * rstd * gamma[l + i * 64] + beta[l + i * 64]);
}

// ---------------- GEMM NT 128x128 (m97 structure) ----------------
template <int EPI>
__global__ __launch_bounds__(256) void gemm128(const bf16* __restrict__ A,
                                               const bf16* __restrict__ Bm, int M, int N, int K,
                                               const float* __restrict__ bias,
                                               bf16* __restrict__ outb) {
  __shared__ __attribute__((aligned(16))) short As[128][64];
  __shared__ __attribute__((aligned(16))) short Bs[128][64];
  const int t = threadIdx.x;
  const int l = t & 63;
  const int w = t >> 6;
  const int wm = w >> 1, wn = w & 1;
  const int bm = blockIdx.y * 128, bn = blockIdx.x * 128;

  f32x4 acc[4][4] = {};
  const int r8 = t >> 3;
  const int c8 = (t & 7) * 8;
  const bf16* Ab = A + (size_t)(bm + r8) * K + c8;
  const bf16* Bb = Bm + (size_t)(bn + r8) * K + c8;

  for (int kt = 0; kt < K; kt += 64) {
    __syncthreads();
#pragma unroll
    for (int i = 0; i < 4; ++i)
      async16(Ab + (size_t)(i * 32) * K + kt, &As[i * 32 + r8][c8]);
#pragma unroll
    for (int i = 0; i < 4; ++i)
      async16(Bb + (size_t)(i * 32) * K + kt, &Bs[i * 32 + r8][c8]);
    __syncthreads();
#pragma unroll
    for (int ks = 0; ks < 2; ++ks) {
      short8 a[4], b[4];
#pragma unroll
      for (int i = 0; i < 4; ++i)
        a[i] = *(const short8*)&As[wm * 64 + i * 16 + (l & 15)][ks * 32 + (l >> 4) * 8];
#pragma unroll
      for (int i = 0; i < 4; ++i)
        b[i] = *(const short8*)&Bs[wn * 64 + i * 16 + (l & 15)][ks * 32 + (l >> 4) * 8];
#pragma unroll
      for (int i = 0; i < 4; ++i)
#pragma unroll
        for (int j = 0; j < 4; ++j) acc[i][j] = MFMA16(a[i], b[j], acc[i][j]);
    }
  }

#pragma unroll
  for (int i = 0; i < 4; ++i) {
#pragma unroll
    for (int j = 0; j < 4; ++j) {
#pragma unroll
      for (int r = 0; r < 4; ++r) {
        int row = bm + wm * 64 + i * 16 + (l >> 4) * 4 + r;
        int col = bn + wn * 64 + j * 16 + (l & 15);
        float v = acc[i][j][r];
        if (EPI == 0) {
          int three = col / 384;
          int rem = col - three * 384;
          int head = rem >> 6;
          int hd = rem & 63;
          int bb = row >> 12;
          int n = row & 4095;
          const size_t QSZ = (size_t)2 * 6 * 4096 * 64;
          if (three < 2) {
            size_t di = ((((size_t)three * 2 + bb) * 6 + head) * 4096 + n) * 64 + hd;
            outb[di] = __float2bfloat16(v);
          } else {
            size_t di = 2 * QSZ + (((size_t)bb * 6 + head) * 64 + hd) * 4096 + n;
            outb[di] = __float2bfloat16(v);
          }
        } else {
          float u = v + bias[col];
          float z = 0.7978845608f * (u + 0.044715f * u * u * u);
          float e = __builtin_amdgcn_exp2f(z * 2.885390082f);
          float th = 1.0f - 2.0f * __builtin_amdgcn_rcpf(e + 1.0f);
          outb[(size_t)row * N + col] = __float2bfloat16(0.5f * u * (1.0f + th));
        }
      }
    }
  }
}

// ---------------- GEMM NT 64x64 dbuf: C = A*B^T + bias + resid (f32) ----------------
__global__ __launch_bounds__(256) void gemm64sq(const bf16* __restrict__ A,
                                                const bf16* __restrict__ Bm, int M, int N, int K,
                                                const float* __restrict__ bias,
                                                const float* __restrict__ resid,
                                                float* __restrict__ outf) {
  __shared__ __attribute__((aligned(16))) short As[2][64][64];
  __shared__ __attribute__((aligned(16))) short Bs[2][64][64];
  const int t = threadIdx.x;
  const int l = t & 63;
  const int w = t >> 6;
  const int wm = w >> 1, wn = w & 1;
  const int bm = blockIdx.y * 64, bn = blockIdx.x * 64;
  const int r8 = t >> 3, c8 = (t & 7) * 8;

  const bf16* Ab = A + (size_t)(bm + r8) * K + c8;
  const bf16* Bb = Bm + (size_t)(bn + r8) * K + c8;

  f32x4 acc[2][2] = {};

  auto stage = [&](int kt, int bf) {
    async16(Ab + kt, &As[bf][r8][c8]);
    async16(Ab + (size_t)32 * K + kt, &As[bf][32 + r8][c8]);
    async16(Bb + kt, &Bs[bf][r8][c8]);
    async16(Bb + (size_t)32 * K + kt, &Bs[bf][32 + r8][c8]);
  };

  stage(0, 0);
  int bf = 0;
  for (int kt = 0; kt < K; kt += 64) {
    __syncthreads();
    if (kt + 64 < K) stage(kt + 64, bf ^ 1);
#pragma unroll
    for (int ks = 0; ks < 2; ++ks) {
      short8 a[2], b[2];
#pragma unroll
      for (int i = 0; i < 2; ++i)
        a[i] = *(const short8*)&As[bf][wm * 32 + i * 16 + (l & 15)][ks * 32 + (l >> 4) * 8];
#pragma unroll
      for (int j = 0; j < 2; ++j)
        b[j] = *(const short8*)&Bs[bf][wn * 32 + j * 16 + (l & 15)][ks * 32 + (l >> 4) * 8];
#pragma unroll
      for (int i = 0; i < 2; ++i)
#pragma unroll
        for (int j = 0; j < 2; ++j) acc[i][j] = MFMA16(a[i], b[j], acc[i][j]);
    }
    bf ^= 1;
  }

#pragma unroll
  for (int i = 0; i < 2; ++i) {
#pragma unroll
    for (int j = 0; j < 2; ++j) {
#pragma unroll
      for (int r = 0; r < 4; ++r) {
        int row = bm + wm * 32 + i * 16 + (l >> 4) * 4 + r;
        int col = bn + wn * 32 + j * 16 + (l & 15);
        size_t di = (size_t)row * N + col;
        outf[di] = acc[i][j][r] + bias[col] + resid[di];
      }
    }
  }
}

// ---------------- attn_obj: QBLK=64, full column sweep, staged, direct ctx1T ----------------
__global__ __launch_bounds__(256) void attn_obj(const bf16* __restrict__ qkvb,
                                                float* __restrict__ aout,
                                                bf16* __restrict__ ctx1T) {
  const int bh = blockIdx.y, b = bh / 3, h = bh - b * 3;
  const int row0 = blockIdx.x * 64;
  const int t = threadIdx.x, l = t & 63, w = t >> 6;

  const size_t HSZ = (size_t)4096 * 64;
  const size_t QSZ = (size_t)2 * 6 * 4096 * 64;
  const bf16* qp = qkvb + (size_t)(b * 6 + h) * HSZ;
  const bf16* kp = qkvb + QSZ + (size_t)(b * 6 + h) * HSZ;
  const bf16* vbase = qkvb + 2 * QSZ + (size_t)((b * 6 + h + 3) * 64) * 4096;

  __shared__ __attribute__((aligned(16))) short Ks[2][64][64];
  __shared__ __attribute__((aligned(16))) short Vs[2][64][64];
  __shared__ __attribute__((aligned(16))) float Sf[4][16][68];

  short8 aq[2];
  {
    int qrow = row0 + w * 16 + (l & 15);
    const bf16* qq = qp + (size_t)qrow * 64 + (l >> 4) * 8;
    aq[0] = *(const short8*)(qq);
    aq[1] = *(const short8*)(qq + 32);
  }

  const int r8 = t >> 3, c8 = (t & 7) * 8;
  const int sc = c8 ^ ((r8 & 7) * 8);

  auto stage = [&](int ct, int bf) {
    const bf16* kb = kp + (size_t)(ct * 64) * 64;
    async16(kb + (size_t)r8 * 64 + sc, &Ks[bf][r8][c8]);
    async16(kb + (size_t)(32 + r8) * 64 + sc, &Ks[bf][32 + r8][c8]);
    const bf16* vb = vbase + ct * 64;
    async16(vb + (size_t)r8 * 4096 + sc, &Vs[bf][r8][c8]);
    async16(vb + (size_t)(32 + r8) * 4096 + sc, &Vs[bf][32 + r8][c8]);
  };

  f32x4 cacc[4] = {};
  const float K1 = -0.18033688f;  // -scale*log2(e)

  float* sfw = &Sf[w][0][0];
  stage(0, 0);
  int bf = 0;
  for (int ct = 0; ct < 64; ++ct) {
    __syncthreads();
    if (ct < 63) stage(ct + 1, bf ^ 1);

    f32x4 sacc[4] = {};
#pragma unroll
    for (int ks = 0; ks < 2; ++ks) {
      short8 bk[4];
#pragma unroll
      for (int j = 0; j < 4; ++j) {
        int rr = j * 16 + (l & 15);
        int ec = (ks * 32 + (l >> 4) * 8) ^ ((rr & 7) * 8);
        bk[j] = *(const short8*)&Ks[bf][rr][ec];
      }
      __builtin_amdgcn_s_setprio(1);
#pragma unroll
      for (int j = 0; j < 4; ++j) sacc[j] = MFMA16(aq[ks], bk[j], sacc[j]);
      __builtin_amdgcn_s_setprio(0);
    }

#pragma unroll
    for (int j = 0; j < 4; ++j) {
#pragma unroll
      for (int r = 0; r < 4; ++r) {
        float v = __builtin_amdgcn_rcpf(1.0f + __builtin_amdgcn_exp2f(sacc[j][r] * K1));
        sfw[((l >> 4) * 4 + r) * 68 + j * 16 + (l & 15)] = v;
      }
    }

    short8 pa[2];
#pragma unroll
    for (int ks = 0; ks < 2; ++ks) {
      const float* sp = &sfw[(l & 15) * 68 + ks * 32 + (l >> 4) * 8];
      f32x4 f0 = *(const f32x4*)sp;
      f32x4 f1 = *(const f32x4*)(sp + 4);
      short8 a;
#pragma unroll
      for (int e = 0; e < 4; ++e) a[e] = f2bs(f0[e]);
#pragma unroll
      for (int e = 0; e < 4; ++e) a[4 + e] = f2bs(f1[e]);
      pa[ks] = a;
    }

    {
      float* ab = aout + (size_t)bh * 4096 * 4096 +
                  (size_t)(row0 + w * 16) * 4096 + ct * 64;
#pragma unroll
      for (int i = 0; i < 4; ++i) {
        f32x4 vv = *(const f32x4*)&sfw[(4 * i + (l >> 4)) * 68 + (l & 15) * 4];
        *(f32x4*)(ab + (size_t)(4 * i + (l >> 4)) * 4096 + (l & 15) * 4) = vv;
      }
    }

#pragma unroll
    for (int ks = 0; ks < 2; ++ks) {
      short8 bv[4];
#pragma unroll
      for (int j = 0; j < 4; ++j) {
        int rr = j * 16 + (l & 15);
        int ec = (ks * 32 + (l >> 4) * 8) ^ ((rr & 7) * 8);
        bv[j] = *(const short8*)&Vs[bf][rr][ec];
      }
      __builtin_amdgcn_s_setprio(1);
#pragma unroll
      for (int j = 0; j < 4; ++j) cacc[j] = MFMA16(pa[ks], bv[j], cacc[j]);
      __builtin_amdgcn_s_setprio(0);
    }
    bf ^= 1;
  }

  // transpose ctx [n][hd] -> ctx1T [bh][hd][n] via LDS (reuse Ks)
  __syncthreads();
  short(*S)[66] = (short(*)[66]) & Ks[0][0][0];
#pragma unroll
  for (int j = 0; j < 4; ++j)
#pragma unroll
    for (int r = 0; r < 4; ++r)
      S[w * 16 + (l >> 4) * 4 + r][j * 16 + (l & 15)] = f2bs(cacc[j][r]);
  __syncthreads();
  const int hd = t >> 2, nb = (t & 3) * 16;
  short8 o0, o1;
#pragma unroll
  for (int k = 0; k < 8; ++k) o0[k] = S[nb + k][hd];
#pragma unroll
  for (int k = 0; k < 8; ++k) o1[k] = S[nb + 8 + k][hd];
  short* dst = (short*)(ctx1T + ((size_t)bh * 64 + hd) * 4096 + row0 + nb);
  *(short8*)dst = o0;
  *(short8*)(dst + 8) = o1;
}

// ---------------- attn_pose: QBLK=128, col-split x4, staged (R7 variant) ----------------
// P = exp(QK^T/8) -> partial ctx + l-sum. Grid: (32, 4, 6).
__global__ __launch_bounds__(256) void attn_pose(const bf16* __restrict__ qkvb,
                                                 const bf16* __restrict__ ctx1T,
                                                 float* __restrict__ part,
                                                 float* __restrict__ lpart) {
  const int bh = blockIdx.z, b = bh / 3, h = bh - b * 3;
  const int row0 = blockIdx.x * 128;
  const int cbase = blockIdx.y * 1024;
  const int t = threadIdx.x, l = t & 63, w = t >> 6;

  const size_t HSZ = (size_t)4096 * 64;
  const size_t QSZ = (size_t)2 * 6 * 4096 * 64;
  const bf16* qp = qkvb + (size_t)(b * 6 + h + 3) * HSZ;
  const bf16* kp = qkvb + QSZ + (size_t)(b * 6 + h + 3) * HSZ;
  const bf16* vbase = ctx1T + (size_t)(bh * 64) * 4096;

  __shared__ __attribute__((aligned(16))) short Ks[2][64][64];
  __shared__ __attribute__((aligned(16))) short Vs[2][64][64];
  __shared__ __attribute__((aligned(16))) float Sf[4][16][68];

  short8 aq[2][2];
#pragma unroll
  for (int rf = 0; rf < 2; ++rf) {
    int qrow = row0 + rf * 64 + w * 16 + (l & 15);
    const bf16* qq = qp + (size_t)qrow * 64 + (l >> 4) * 8;
    aq[rf][0] = *(const short8*)(qq);
    aq[rf][1] = *(const short8*)(qq + 32);
  }

  const int r8 = t >> 3, c8 = (t & 7) * 8;
  const int sc = c8 ^ ((r8 & 7) * 8);

  auto stage = [&](int ct, int bf) {
    const bf16* kb = kp + (size_t)(cbase + ct * 64) * 64;
    async16(kb + (size_t)r8 * 64 + sc, &Ks[bf][r8][c8]);
    async16(kb + (size_t)(32 + r8) * 64 + sc, &Ks[bf][32 + r8][c8]);
    const bf16* vb = vbase + cbase + ct * 64;
    async16(vb + (size_t)r8 * 4096 + sc, &Vs[bf][r8][c8]);
    async16(vb + (size_t)(32 + r8) * 4096 + sc, &Vs[bf][32 + r8][c8]);
  };

  f32x4 cacc[2][4] = {};
  float lp[2][4] = {};
  const float K2 = 0.18033688f;

  float* sfw = &Sf[w][0][0];
  stage(0, 0);
  int bf = 0;
  for (int ct = 0; ct < 16; ++ct) {
    __syncthreads();
    if (ct < 15) stage(ct + 1, bf ^ 1);

    f32x4 sacc[2][4] = {};
#pragma unroll
    for (int ks = 0; ks < 2; ++ks) {
      short8 bk[4];
#pragma unroll
      for (int j = 0; j < 4; ++j) {
        int rr = j * 16 + (l & 15);
        int ec = (ks * 32 + (l >> 4) * 8) ^ ((rr & 7) * 8);
        bk[j] = *(const short8*)&Ks[bf][rr][ec];
      }
      __builtin_amdgcn_s_setprio(1);
#pragma unroll
      for (int rf = 0; rf < 2; ++rf)
#pragma unroll
        for (int j = 0; j < 4; ++j)
          sacc[rf][j] = MFMA16(aq[rf][ks], bk[j], sacc[rf][j]);
      __builtin_amdgcn_s_setprio(0);
    }

    short8 pa[2][2];
#pragma unroll
    for (int rf = 0; rf < 2; ++rf) {
#pragma unroll
      for (int j = 0; j < 4; ++j) {
#pragma unroll
        for (int r = 0; r < 4; ++r) {
          float v = __builtin_amdgcn_exp2f(sacc[rf][j][r] * K2);
          lp[rf][r] += v;
          sfw[((l >> 4) * 4 + r) * 68 + j * 16 + (l & 15)] = v;
        }
      }
#pragma unroll
      for (int ks = 0; ks < 2; ++ks) {
        const float* sp = &sfw[(l & 15) * 68 + ks * 32 + (l >> 4) * 8];
        f32x4 f0 = *(const f32x4*)sp;
        f32x4 f1 = *(const f32x4*)(sp + 4);
        short8 a;
#pragma unroll
        for (int e = 0; e < 4; ++e) a[e] = f2bs(f0[e]);
#pragma unroll
        for (int e = 0; e < 4; ++e) a[4 + e] = f2bs(f1[e]);
        pa[rf][ks] = a;
      }
    }

#pragma unroll
    for (int ks = 0; ks < 2; ++ks) {
      short8 bv[4];
#pragma unroll
      for (int j = 0; j < 4; ++j) {
        int rr = j * 16 + (l & 15);
        int ec = (ks * 32 + (l >> 4) * 8) ^ ((rr & 7) * 8);
        bv[j] = *(const short8*)&Vs[bf][rr][ec];
      }
      __builtin_amdgcn_s_setprio(1);
#pragma unroll
      for (int rf = 0; rf < 2; ++rf)
#pragma unroll
        for (int j = 0; j < 4; ++j)
          cacc[rf][j] = MFMA16(pa[rf][ks], bv[j], cacc[rf][j]);
      __builtin_amdgcn_s_setprio(0);
    }
    bf ^= 1;
  }

#pragma unroll
  for (int rf = 0; rf < 2; ++rf) {
    float* pb = part + ((size_t)(blockIdx.y * 6 + bh) * 4096 + row0 + rf * 64 + w * 16) * 64;
#pragma unroll
    for (int j = 0; j < 4; ++j)
#pragma unroll
      for (int r = 0; r < 4; ++r)
        pb[(size_t)((l >> 4) * 4 + r) * 64 + j * 16 + (l & 15)] = cacc[rf][j][r];
  }

#pragma unroll
  for (int rf = 0; rf < 2; ++rf) {
#pragma unroll
    for (int r = 0; r < 4; ++r) {
#pragma unroll
      for (int m = 1; m < 16; m <<= 1) lp[rf][r] += __shfl_xor(lp[rf][r], m);
    }
    if ((l & 15) == 0) {
      float* lb = lpart + (size_t)(blockIdx.y * 6 + bh) * 4096 + row0 + rf * 64 + w * 16 + (l >> 4) * 4;
#pragma unroll
      for (int r = 0; r < 4; ++r) lb[r] = lp[rf][r];
    }
  }
}

// ---------------- reduce pose partials -> ctxf bf16 [b][n][192] ----------------
__global__ __launch_bounds__(256) void reduce_pose(const float* __restrict__ part,
                                                   const float* __restrict__ lpart,
                                                   bf16* __restrict__ ctxf) {
  const int idx = blockIdx.x * 256 + threadIdx.x;
  const int hd4 = idx & 15;
  const int n = (idx >> 4) & 4095;
  const int bh = idx >> 16;
  const size_t CS = (size_t)6 * 4096 * 64, CL = (size_t)6 * 4096;
  f32x4 s = {};
  float lt = 0.f;
#pragma unroll
  for (int c = 0; c < 4; ++c) {
    s += *(const f32x4*)(part + c * CS + ((size_t)bh * 4096 + n) * 64 + hd4 * 4);
    lt += lpart[c * CL + (size_t)bh * 4096 + n];
  }
  float inv = 1.0f / lt;
  int b = bh / 3, h = bh - b * 3;
  s16x4 o;
#pragma unroll
  for (int e = 0; e < 4; ++e) o[e] = f2bs(s[e] * inv);
  *(s16x4*)(ctxf + ((size_t)b * 4096 + n) * 192 + h * 64 + hd4 * 4) = o;
}

// ---------------- launch ----------------
extern "C" void kernel_launch(void* const* d_in, const int* in_sizes, int n_in,
                              void* d_out, int out_size, void* d_ws, size_t ws_size,
                              hipStream_t stream) {
  const float* x      = (const float*)d_in[0];
  const float* qkv_w  = (const float*)d_in[1];
  const float* proj_w = (const float*)d_in[2];
  const float* proj_b = (const float*)d_in[3];
  const float* gamma1 = (const float*)d_in[4];
  const float* beta1  = (const float*)d_in[5];
  const float* gamma2 = (const float*)d_in[6];
  const float* beta2  = (const float*)d_in[7];
  const float* fc1_w  = (const float*)d_in[8];
  const float* fc1_b  = (const float*)d_in[9];
  const float* fc2_w  = (const float*)d_in[10];
  const float* fc2_b  = (const float*)d_in[11];

  float* out_x = (float*)d_out;
  float* out_attn = out_x + (size_t)2 * 4096 * 384;

  char* ws = (char*)d_ws;
  size_t off = 0;
  auto alloc = [&](size_t bytes) -> void* {
    void* p = ws + off;
    off += (bytes + 255) & ~(size_t)255;
    return p;
  };
  bf16* qkv_w_b  = (bf16*)alloc((size_t)1152 * 384 * 2);
  bf16* proj_w_b = (bf16*)alloc((size_t)384 * 192 * 2);
  bf16* fc1_w_b  = (bf16*)alloc((size_t)1536 * 384 * 2);
  bf16* fc2_w_b  = (bf16*)alloc((size_t)384 * 1536 * 2);
  bf16* h1    = (bf16*)alloc((size_t)8192 * 384 * 2);
  bf16* qkvb  = (bf16*)alloc((size_t)3 * 2 * 6 * 4096 * 64 * 2);
  float* cpp  = (float*)alloc((size_t)4 * 6 * 4096 * 64 * 4);
  float* lpp  = (float*)alloc((size_t)4 * 6 * 4096 * 4);
  bf16* ctx1T = (bf16*)alloc((size_t)6 * 64 * 4096 * 2);
  bf16* ctxf  = (bf16*)alloc((size_t)2 * 4096 * 192 * 2);
  float* x2   = (float*)alloc((size_t)8192 * 384 * 4);
  bf16* h2    = (bf16*)alloc((size_t)8192 * 384 * 2);
  bf16* h3    = (bf16*)alloc((size_t)8192 * 1536 * 2);

  ln_fwd<true><<<3704, 256, 0, stream>>>(x, gamma1, beta1, h1,
                                         qkv_w, proj_w, fc1_w, fc2_w,
                                         qkv_w_b, proj_w_b, fc1_w_b, fc2_w_b);

  gemm128<0><<<dim3(9, 64), 256, 0, stream>>>(h1, qkv_w_b, 8192, 1152, 384,
                                              nullptr, qkvb);

  attn_obj<<<dim3(64, 6), 256, 0, stream>>>(qkvb, out_attn, ctx1T);
  attn_pose<<<dim3(32, 4, 6), 256, 0, stream>>>(qkvb, ctx1T, cpp, lpp);
  reduce_pose<<<1536, 256, 0, stream>>>(cpp, lpp, ctxf);

  gemm64sq<<<dim3(6, 128), 256, 0, stream>>>(ctxf, proj_w_b, 8192, 384, 192,
                                             proj_b, x, x2);
  ln_fwd<false><<<2048, 256, 0, stream>>>(x2, gamma2, beta2, h2,
                                          nullptr, nullptr, nullptr, nullptr,
                                          nullptr, nullptr, nullptr, nullptr);
  gemm128<2><<<dim3(12, 64), 256, 0, stream>>>(h2, fc1_w_b, 8192, 1536, 384,
                                               fc1_b, h3);
  gemm64sq<<<dim3(6, 128), 256, 0, stream>>>(h3, fc2_w_b, 8192, 384, 1536,
                                             fc2_b, x2, out_x);
}